// Round 1
// baseline (1314.200 us; speedup 1.0000x reference)
//
#include <hip/hip_runtime.h>
#include <hip/hip_bf16.h>
#include <cstddef>

typedef __hip_bfloat16 bf16;
typedef float floatx4 __attribute__((ext_vector_type(4)));
typedef short shortx8 __attribute__((ext_vector_type(8)));

#define NROWS 8192
#define INDIM 1024
#define OUTDIM 8192
#define CM1 8191

// ---------------------------------------------------------------------------
// Segment accumulation: sums[label[i]] += x[i], cnts[label[i]] += 1
// ---------------------------------------------------------------------------
__global__ __launch_bounds__(256) void seg_acc_kernel(
    const float* __restrict__ x, const int* __restrict__ labels,
    float* __restrict__ sums, int* __restrict__ cnts) {
  int i = blockIdx.x;
  int l = labels[i];
  const float* xr = x + (size_t)i * INDIM;
  float* sr = sums + (size_t)l * INDIM;
  for (int d = threadIdx.x; d < INDIM; d += 256) atomicAdd(&sr[d], xr[d]);
  if (threadIdx.x == 0) atomicAdd(&cnts[l], 1);
}

// ---------------------------------------------------------------------------
// f32 -> bf16 conversion (optionally zero-padded tail)
// ---------------------------------------------------------------------------
__global__ __launch_bounds__(256) void cvt_kernel(
    const float* __restrict__ in, bf16* __restrict__ out, long n) {
  long i = (long)blockIdx.x * 256 + threadIdx.x;
  if (i < n) out[i] = __float2bfloat16(in[i]);
}

__global__ __launch_bounds__(256) void cvt_pad_kernel(
    const float* __restrict__ in, bf16* __restrict__ out, long n_in, long n_out) {
  long i = (long)blockIdx.x * 256 + threadIdx.x;
  if (i < n_out) out[i] = __float2bfloat16(i < n_in ? in[i] : 0.0f);
}

// ---------------------------------------------------------------------------
// Build v^T [INDIM][OUTDIM] bf16 (column c in [0,CM1) = class c+1; col CM1 = 0)
// v[c] = new_hist[c] * (1-MU)/(1-MU^clamped)
// ---------------------------------------------------------------------------
__global__ __launch_bounds__(256) void make_vt_kernel(
    const float* __restrict__ sums, const int* __restrict__ cnts,
    const float* __restrict__ hist, const int* __restrict__ hist_cnt,
    bf16* __restrict__ vT) {
  size_t idx = (size_t)blockIdx.x * 256 + threadIdx.x;  // d*8192 + c
  int c = (int)(idx & (OUTDIM - 1));
  int d = (int)(idx >> 13);
  float val = 0.0f;
  if (c < CM1) {
    int cnt = cnts[c + 1];
    bool present = cnt > 0;
    float mean = sums[(size_t)(c + 1) * INDIM + d] / fmaxf((float)cnt, 1.0f);
    float h = hist[(size_t)c * INDIM + d];
    float nh = present ? (0.9f * h + mean) : h;
    int nc = hist_cnt[c] + (present ? 1 : 0);
    float clamped = (float)(nc > 1 ? nc : 1);
    float scale = 0.1f / (1.0f - powf(0.9f, clamped));
    val = nh * scale;
  }
  vT[idx] = __float2bfloat16(val);
}

// ---------------------------------------------------------------------------
// GEMM: C[m][n] = sum_k A[m][k] * B[n][k]   (A row-major [M][K], B row-major [N][K])
// 128x128 tile, BK=64, bf16 16x16x32 MFMA, 256 threads (4 waves, 2x2 of 64x64)
// ---------------------------------------------------------------------------
__device__ __forceinline__ void store_c(float* p, float v) { *p = v; }
__device__ __forceinline__ void store_c(bf16* p, float v) { *p = __float2bfloat16(v); }

template <typename OutT>
__global__ __launch_bounds__(256) void gemm_bt_kernel(
    const bf16* __restrict__ A, const bf16* __restrict__ B, OutT* __restrict__ C,
    int K, int ldc) {
  __shared__ bf16 As[128][72];
  __shared__ bf16 Bs[128][72];
  const int t = threadIdx.x;
  const int lane = t & 63;
  const int wave = t >> 6;
  const int bm = blockIdx.y * 128;
  const int bn = blockIdx.x * 128;
  const int wm = (wave >> 1) * 64;
  const int wn = (wave & 1) * 64;

  floatx4 acc[4][4];
#pragma unroll
  for (int i = 0; i < 4; i++)
#pragma unroll
    for (int j = 0; j < 4; j++) acc[i][j] = (floatx4){0.f, 0.f, 0.f, 0.f};

  const int r = lane & 15;      // row within 16 / output col
  const int q = lane >> 4;      // k-chunk selector 0..3

  for (int k0 = 0; k0 < K; k0 += 64) {
    __syncthreads();
#pragma unroll
    for (int i = 0; i < 4; i++) {
      int c = t + i * 256;              // chunk id 0..1023
      int row = c >> 3;
      int col = (c & 7) << 3;
      *(uint4*)(&As[row][col]) = *(const uint4*)(A + (size_t)(bm + row) * K + k0 + col);
      *(uint4*)(&Bs[row][col]) = *(const uint4*)(B + (size_t)(bn + row) * K + k0 + col);
    }
    __syncthreads();
#pragma unroll
    for (int kk = 0; kk < 64; kk += 32) {
      shortx8 af[4], bf[4];
#pragma unroll
      for (int i = 0; i < 4; i++) {
        af[i] = *(const shortx8*)(&As[wm + i * 16 + r][kk + q * 8]);
        bf[i] = *(const shortx8*)(&Bs[wn + i * 16 + r][kk + q * 8]);
      }
#pragma unroll
      for (int i = 0; i < 4; i++)
#pragma unroll
        for (int j = 0; j < 4; j++)
          acc[i][j] = __builtin_amdgcn_mfma_f32_16x16x32_bf16(af[i], bf[j], acc[i][j], 0, 0, 0);
    }
  }

  // C/D layout: n = lane&15, m = (lane>>4)*4 + reg
#pragma unroll
  for (int i = 0; i < 4; i++)
#pragma unroll
    for (int j = 0; j < 4; j++)
#pragma unroll
      for (int rr = 0; rr < 4; rr++) {
        int m = bm + wm + i * 16 + q * 4 + rr;
        int n = bn + wn + j * 16 + r;
        store_c(&C[(size_t)m * ldc + n], acc[i][j][rr]);
      }
}

// ---------------------------------------------------------------------------
// Row softmax over first CM1 cols of wl (bf16, ld=OUTDIM), add bias; col CM1 -> 0
// ---------------------------------------------------------------------------
__global__ __launch_bounds__(256) void softmax_rows_kernel(
    bf16* __restrict__ wl, const float* __restrict__ bias) {
  __shared__ float red[4];
  const int t = threadIdx.x;
  bf16* p = wl + (size_t)blockIdx.x * OUTDIM;
  float vals[32];
  float mx = -1e30f;
#pragma unroll
  for (int i = 0; i < 32; i++) {
    int col = i * 256 + t;
    float v = -1e30f;
    if (col < CM1) v = __bfloat162float(p[col]) + bias[col];
    vals[i] = v;
    mx = fmaxf(mx, v);
  }
  for (int o = 32; o; o >>= 1) mx = fmaxf(mx, __shfl_down(mx, o, 64));
  if ((t & 63) == 0) red[t >> 6] = mx;
  __syncthreads();
  mx = fmaxf(fmaxf(red[0], red[1]), fmaxf(red[2], red[3]));
  __syncthreads();
  float s = 0.f;
#pragma unroll
  for (int i = 0; i < 32; i++) {
    int col = i * 256 + t;
    float e = (col < CM1) ? __expf(vals[i] - mx) : 0.f;
    vals[i] = e;
    s += e;
  }
  for (int o = 32; o; o >>= 1) s += __shfl_down(s, o, 64);
  if ((t & 63) == 0) red[t >> 6] = s;
  __syncthreads();
  s = red[0] + red[1] + red[2] + red[3];
  float rs = 1.0f / s;
#pragma unroll
  for (int i = 0; i < 32; i++) {
    int col = i * 256 + t;
    p[col] = __float2bfloat16(vals[i] * rs);
  }
}

// ---------------------------------------------------------------------------
// g = sigmoid(x . wg + b); feat = bf16(g*x + (1-g)*sub)
// ---------------------------------------------------------------------------
__global__ __launch_bounds__(256) void g_feat_kernel(
    const float* __restrict__ x, const float* __restrict__ wg,
    const float* __restrict__ wgb, const bf16* __restrict__ sub,
    bf16* __restrict__ feat) {
  __shared__ float red[4];
  const int t = threadIdx.x;
  const float* xr = x + (size_t)blockIdx.x * INDIM;
  float dot = 0.f;
#pragma unroll
  for (int i = 0; i < 4; i++) {
    int d = i * 256 + t;
    dot += xr[d] * wg[d];
  }
  for (int o = 32; o; o >>= 1) dot += __shfl_down(dot, o, 64);
  if ((t & 63) == 0) red[t >> 6] = dot;
  __syncthreads();
  dot = red[0] + red[1] + red[2] + red[3];
  float g = 1.0f / (1.0f + __expf(-(dot + wgb[0])));
  const bf16* sr = sub + (size_t)blockIdx.x * INDIM;
  bf16* fr = feat + (size_t)blockIdx.x * INDIM;
#pragma unroll
  for (int i = 0; i < 4; i++) {
    int d = i * 256 + t;
    float f = g * xr[d] + (1.0f - g) * __bfloat162float(sr[d]);
    fr[d] = __float2bfloat16(f);
  }
}

// ---------------------------------------------------------------------------
// Cross-entropy accumulation over rows
// ---------------------------------------------------------------------------
__global__ __launch_bounds__(256) void ce_kernel(
    const float* __restrict__ logits, const int* __restrict__ labels,
    float* __restrict__ acc) {
  __shared__ float red[4];
  const int t = threadIdx.x;
  const float* p = logits + (size_t)blockIdx.x * OUTDIM;
  float vals[32];
  float mx = -1e30f;
#pragma unroll
  for (int i = 0; i < 32; i++) {
    float v = p[i * 256 + t];
    vals[i] = v;
    mx = fmaxf(mx, v);
  }
  for (int o = 32; o; o >>= 1) mx = fmaxf(mx, __shfl_down(mx, o, 64));
  if ((t & 63) == 0) red[t >> 6] = mx;
  __syncthreads();
  mx = fmaxf(fmaxf(red[0], red[1]), fmaxf(red[2], red[3]));
  __syncthreads();
  float s = 0.f;
#pragma unroll
  for (int i = 0; i < 32; i++) s += __expf(vals[i] - mx);
  for (int o = 32; o; o >>= 1) s += __shfl_down(s, o, 64);
  if ((t & 63) == 0) red[t >> 6] = s;
  __syncthreads();
  if (t == 0) {
    s = red[0] + red[1] + red[2] + red[3];
    int l = labels[blockIdx.x];
    if (l >= 0) {
      float nll = mx + logf(s) - p[l];
      atomicAdd(&acc[0], nll);
      atomicAdd(&acc[1], 1.0f);
    }
  }
}

__global__ void finalize_kernel(const float* __restrict__ acc, float* __restrict__ out) {
  out[0] = acc[0] / fmaxf(acc[1], 1.0f);
}

// ---------------------------------------------------------------------------
extern "C" void kernel_launch(void* const* d_in, const int* in_sizes, int n_in,
                              void* d_out, int out_size, void* d_ws, size_t ws_size,
                              hipStream_t stream) {
  const float* x        = (const float*)d_in[0];
  const float* x_ctx    = (const float*)d_in[1];
  const int*   labels   = (const int*)d_in[2];
  const float* cls      = (const float*)d_in[3];
  const float* ctxq_w   = (const float*)d_in[4];
  const float* ctxq_b   = (const float*)d_in[5];
  const float* wg_w     = (const float*)d_in[6];
  const float* wg_b     = (const float*)d_in[7];
  const float* hist     = (const float*)d_in[8];
  const int*   hist_cnt = (const int*)d_in[9];
  float* out = (float*)d_out;

  char* ws = (char*)d_ws;
  float* sums   = (float*)(ws + 0);            // 8192*1024*4 = 33554432
  int*   cnts   = (int*)  (ws + 33554432);     // 32768
  float* acc    = (float*)(ws + 33587200);     // 256
  bf16* xctx_bf = (bf16*) (ws + 33587456);     // 16777216
  bf16* wq_bf   = (bf16*) (ws + 50364672);     // 16777216 (padded row 8191 = 0)
  bf16* cls_bf  = (bf16*) (ws + 67141888);     // 16777216
  bf16* vT      = (bf16*) (ws + 83919104);     // 16777216 [1024][8192]
  bf16* wl      = (bf16*) (ws + 100696320);    // 134217728 [8192][8192]
  bf16* sub_bf  = (bf16*) (ws + 234914048);    // 16777216
  bf16* feat_bf = (bf16*) (ws + 251691264);    // 16777216
  // total: 268468480 bytes

  // zero sums + cnts + acc
  hipMemsetAsync(ws, 0, 33587456 + 256, stream);

  seg_acc_kernel<<<NROWS, 256, 0, stream>>>(x, labels, sums, cnts);
  cvt_kernel<<<32768, 256, 0, stream>>>(x_ctx, xctx_bf, (long)NROWS * INDIM);
  cvt_pad_kernel<<<32768, 256, 0, stream>>>(ctxq_w, wq_bf, (long)CM1 * INDIM,
                                            (long)OUTDIM * INDIM);
  cvt_kernel<<<32768, 256, 0, stream>>>(cls, cls_bf, (long)OUTDIM * INDIM);
  make_vt_kernel<<<32768, 256, 0, stream>>>(sums, cnts, hist, hist_cnt, vT);

  // GEMM1: w_logits = x_ctx @ ctx_q_w^T  [8192 x 8192], K=1024
  gemm_bt_kernel<bf16><<<dim3(64, 64), 256, 0, stream>>>(xctx_bf, wq_bf, wl, 1024, OUTDIM);
  softmax_rows_kernel<<<NROWS, 256, 0, stream>>>(wl, ctxq_b);
  // GEMM2: substitute = w @ v  == w [8192 x 8192(K)] . vT [1024 x 8192(K)]^T
  gemm_bt_kernel<bf16><<<dim3(8, 64), 256, 0, stream>>>(wl, vT, sub_bf, OUTDIM, INDIM);
  g_feat_kernel<<<NROWS, 256, 0, stream>>>(x, wg_w, wg_b, sub_bf, feat_bf);
  // GEMM3: logits = feat @ classifier^T  [8192 x 8192], K=1024 -> d_out+1 (fp32)
  gemm_bt_kernel<float><<<dim3(64, 64), 256, 0, stream>>>(feat_bf, cls_bf, out + 1, 1024, OUTDIM);
  ce_kernel<<<NROWS, 256, 0, stream>>>(out + 1, labels, acc);
  finalize_kernel<<<1, 1, 0, stream>>>(acc, out);
}